// Round 1
// baseline (60.371 us; speedup 1.0000x reference)
//
#include <hip/hip_runtime.h>

// RNN(tanh) fused forward: xin-proj + scan + fc + exp in one kernel.
// T=512, B=32768, H=2, IN=2, OUT=1. One thread per batch element.

#define T_STEPS 512
#define BATCH   32768
#define PF      8   // prefetch depth (timesteps of x held in registers)

__global__ __launch_bounds__(64) void rnn_fused_kernel(
    const float2* __restrict__ x,     // [T][B] as float2 (n_in=2)
    const float*  __restrict__ W_ih,  // [2][2]
    const float*  __restrict__ W_hh,  // [2][2]
    const float*  __restrict__ b_ih,  // [2]
    const float*  __restrict__ b_hh,  // [2]
    const float*  __restrict__ fc_w,  // [1][2]
    const float*  __restrict__ fc_b,  // [1]
    float*        __restrict__ out)   // [T*B] output, then [B][2] h_last
{
    const int b = blockIdx.x * 64 + threadIdx.x;

    // Wave-uniform weights (scalar-cached).
    const float w00 = W_ih[0], w01 = W_ih[1], w10 = W_ih[2], w11 = W_ih[3];
    const float u00 = W_hh[0], u01 = W_hh[1], u10 = W_hh[2], u11 = W_hh[3];
    const float bi0 = b_ih[0] + b_hh[0], bi1 = b_ih[1] + b_hh[1];
    const float f0 = fc_w[0], f1 = fc_w[1], fb = fc_b[0];
    const float L2E  = 1.44269504088896340736f;  // log2(e)
    const float L2E2 = 2.0f * L2E;

    const float2* xp = x + b;
    float* op = out + b;
    float* hp = out + (size_t)T_STEPS * BATCH;

    float h0 = 0.0f, h1 = 0.0f;

    float2 buf[PF];
    #pragma unroll
    for (int i = 0; i < PF; ++i) buf[i] = xp[(size_t)i * BATCH];

    for (int t0 = 0; t0 < T_STEPS; t0 += PF) {
        float2 nbuf[PF];
        const bool more = (t0 + PF) < T_STEPS;
        if (more) {
            #pragma unroll
            for (int i = 0; i < PF; ++i)
                nbuf[i] = xp[(size_t)(t0 + PF + i) * BATCH];
        }
        #pragma unroll
        for (int i = 0; i < PF; ++i) {
            const float x0 = buf[i].x, x1 = buf[i].y;
            // input projection + bias
            float a0 = fmaf(x0, w00, fmaf(x1, w01, bi0));
            float a1 = fmaf(x0, w10, fmaf(x1, w11, bi1));
            // recurrent contribution: h @ W_hh^T
            a0 = fmaf(h0, u00, fmaf(h1, u01, a0));
            a1 = fmaf(h0, u10, fmaf(h1, u11, a1));
            // tanh(a) = 1 - 2/(exp(2a)+1); saturates correctly at +/-inf
            const float e0 = __builtin_amdgcn_exp2f(a0 * L2E2);
            const float e1 = __builtin_amdgcn_exp2f(a1 * L2E2);
            h0 = fmaf(-2.0f, __builtin_amdgcn_rcpf(e0 + 1.0f), 1.0f);
            h1 = fmaf(-2.0f, __builtin_amdgcn_rcpf(e1 + 1.0f), 1.0f);
            // fused projection + exp
            const float z = fmaf(h0, f0, fmaf(h1, f1, fb));
            op[(size_t)(t0 + i) * BATCH] = __builtin_amdgcn_exp2f(z * L2E);
        }
        if (more) {
            #pragma unroll
            for (int i = 0; i < PF; ++i) buf[i] = nbuf[i];
        }
    }

    // h_last: [1][B][2]
    hp[2 * b + 0] = h0;
    hp[2 * b + 1] = h1;
}

extern "C" void kernel_launch(void* const* d_in, const int* in_sizes, int n_in,
                              void* d_out, int out_size, void* d_ws, size_t ws_size,
                              hipStream_t stream) {
    const float2* x    = (const float2*)d_in[0];
    const float*  W_ih = (const float*)d_in[1];
    const float*  W_hh = (const float*)d_in[2];
    const float*  b_ih = (const float*)d_in[3];
    const float*  b_hh = (const float*)d_in[4];
    const float*  fc_w = (const float*)d_in[5];
    const float*  fc_b = (const float*)d_in[6];
    float* out = (float*)d_out;

    rnn_fused_kernel<<<dim3(BATCH / 64), dim3(64), 0, stream>>>(
        x, W_ih, W_hh, b_ih, b_hh, fc_w, fc_b, out);
}